// Round 16
// baseline (516.780 us; speedup 1.0000x reference)
//
#include <hip/hip_runtime.h>
#include <math.h>

#define DIN 256
#define HDIM 128
#define NCRIT 10

typedef __bf16 bf16;
typedef bf16 bf16x8 __attribute__((ext_vector_type(8)));
typedef float f32x4 __attribute__((ext_vector_type(4)));
typedef float f32x2 __attribute__((ext_vector_type(2)));

static inline size_t alignup(size_t x, size_t a) { return (x + a - 1) & ~(a - 1); }

__device__ inline float bflo(unsigned v) { return __uint_as_float(v << 16); }
__device__ inline float bfhi(unsigned v) { return __uint_as_float(v & 0xffff0000u); }

__device__ inline bf16x8 cvt8(float4 v0, float4 v1) {
    bf16x8 w;
    w[0] = (bf16)v0.x; w[1] = (bf16)v0.y; w[2] = (bf16)v0.z; w[3] = (bf16)v0.w;
    w[4] = (bf16)v1.x; w[5] = (bf16)v1.y; w[6] = (bf16)v1.z; w[7] = (bf16)v1.w;
    return w;
}

__device__ inline unsigned char f32_fp8(float f) {
    return (unsigned char)(__builtin_amdgcn_cvt_pk_fp8_f32(f, f, 0, false) & 0xFF);
}

__device__ inline void gl_lds16(const void* g, void* l) {
    __builtin_amdgcn_global_load_lds(
        (const __attribute__((address_space(1))) unsigned*)g,
        (__attribute__((address_space(3))) unsigned*)l, 16, 0, 0);
}

// ---------- k1: build WcatT (chunk layout) + hist ----------
// Logical Wcat rows 0..127=Wl, 128..255=Wr, 256..266=Wepi@Wres, 267..271=0.
// WcatT: element (row c, k) at byte ((k>>3)*272 + c)*16 + (k&7)*2  (8 k-elems/chunk)
__global__ void k_histw(const int* __restrict__ dst, int E, int* __restrict__ cnt,
                        int* __restrict__ epos, int nW,
                        const float* __restrict__ Wl, const float* __restrict__ Wr,
                        const float* __restrict__ Wres,
                        const float* __restrict__ wscore, const float* __restrict__ wcrit,
                        bf16* __restrict__ WcatT) {
    int t = threadIdx.x;
    int b = blockIdx.x;
    if (b < 64) {
        int base = (b * 256 + t) * 4;          // element index over 256 rows x 256 k
        int r = base >> 8;
        int c0 = base & 255;                    // k0, multiple of 4
        const float* W = (r < 128) ? Wl : Wr;
        float4 v = *(const float4*)&W[(size_t)(r & 127) * 256 + c0];
        bf16 o[4] = {(bf16)v.x, (bf16)v.y, (bf16)v.z, (bf16)v.w};
        char* d = (char*)WcatT + ((((size_t)(c0 >> 3) * 272 + r) << 4) + ((c0 & 7) << 1));
        *(uint2*)d = *(const uint2*)o;
    } else if (b < 80) {
        int q = b - 64;                         // logical row 256+q
        int k = t;
        float s = 0.f;
        if (q < 11) {
            const float* wepi = (q == 0) ? wscore : &wcrit[(size_t)(q - 1) * HDIM];
            for (int c = 0; c < HDIM; ++c)
                s += wepi[c] * Wres[(size_t)c * 256 + k];
        }
        char* d = (char*)WcatT + ((((size_t)(k >> 3) * 272 + 256 + q) << 4) + ((k & 7) << 1));
        *(bf16*)d = (bf16)s;
    } else {
        int i = (b - nW) * 256 + t;
        if (i < E) epos[i] = atomicAdd(&cnt[dst[i]], 1);
    }
}

// ---------- k2: alloc (wave scan + atomic base) ----------
__global__ void k_alloc(const int* __restrict__ cnt, int n, int* __restrict__ off,
                        int* __restrict__ total) {
    int i = blockIdx.x * 256 + threadIdx.x;
    int lane = threadIdx.x & 63;
    int v = (i < n) ? cnt[i] : 0;
    int s = v;
    #pragma unroll
    for (int d = 1; d < 64; d <<= 1) {
        int t = __shfl_up(s, d, 64);
        if (lane >= d) s += t;
    }
    int excl = s - v;
    int wtot = __shfl(s, 63, 64);
    int base = 0;
    if (lane == 63) base = atomicAdd(total, wtot);
    base = __shfl(base, 63, 64);
    if (i < n) off[i] = base + excl;
}

// ---------- k3: barrier-free GEMM (B in LDS, x reg-preload, direct frag stores) ----------
// [y | zr | w] = x @ Wcat^T (272 cols); per wave: independent 16-row tile.
// B LDS = WcatT image (linear copy): chunk (skg, c) at (skg*272+c)*16
__global__ __launch_bounds__(512) void k_gemm(
    const float* __restrict__ x, const bf16* __restrict__ WcatT, int n,
    unsigned char* __restrict__ yq, bf16* __restrict__ z, float* __restrict__ w,
    const int* __restrict__ src, const int* __restrict__ dstv,
    const int* __restrict__ epos, int E,
    const int* __restrict__ off, int* __restrict__ sidx)
{
    __shared__ __align__(16) char smem[139264];   // 136KB = 32 skg x 272 c x 16B
    int t = threadIdx.x;
    int wv = t >> 6, lane = t & 63;
    int l15 = lane & 15, kq = lane >> 4;

    // stage B: linear 136KB copy, global_load_lds, coalesced + conflict-free
    {
        int cbase0 = wv * 64;   // wave-uniform chunk base within each 512-group
        #pragma unroll
        for (int i = 0; i < 17; i++) {
            int cbase = i * 512 + cbase0;
            gl_lds16((const char*)WcatT + (((size_t)cbase + lane) << 4),
                     smem + ((size_t)cbase << 4));
        }
    }
    __syncthreads();   // the only block-wide barrier

    int nTiles = (n + 127) >> 7;
    for (int tile = blockIdx.x; tile < nTiles; tile += gridDim.x) {
        int rowb = tile * 128 + wv * 16;
        int myrow = rowb + l15;
        const float* ap = x + (size_t)(myrow < n ? myrow : (n - 1)) * 256 + kq * 8;

        // preload the whole tile's x into registers (16 loads in flight)
        float4 xa[8], xb[8];
        #pragma unroll
        for (int s = 0; s < 8; s++) {
            xa[s] = *(const float4*)(ap + s * 32);
            xb[s] = *(const float4*)(ap + s * 32 + 4);
        }

        f32x4 acc[17];
        #pragma unroll
        for (int C = 0; C < 17; C++) acc[C] = (f32x4){0.f, 0.f, 0.f, 0.f};

        #pragma unroll
        for (int s = 0; s < 8; s++) {
            bf16x8 afr = cvt8(xa[s], xb[s]);
            int sbase = ((s * 4 + kq) * 272 + l15) << 4;
            #pragma unroll
            for (int C = 0; C < 17; C++) {
                bf16x8 b = *(const bf16x8*)(smem + sbase + C * 256);
                acc[C] = __builtin_amdgcn_mfma_f32_16x16x32_bf16(afr, b, acc[C], 0, 0, 0);
            }
        }

        // direct fragment stores: lane owns col C*16+l15, rows rowb+kq*4+j
        #pragma unroll
        for (int j = 0; j < 4; j++) {
            int gr = rowb + kq * 4 + j;
            if (gr >= n) continue;
            unsigned char* yrow = yq + (size_t)gr * 128 + l15;
            bf16* zrow = z + (size_t)gr * 128 + l15;
            #pragma unroll
            for (int C = 0; C < 8; C++)
                yrow[C * 16] = f32_fp8(acc[C][j]);
            #pragma unroll
            for (int C = 8; C < 16; C++)
                zrow[(C - 8) * 16] = (bf16)acc[C][j];
            w[(size_t)gr * 16 + l15] = acc[16][j];
        }
    }

    // scatter tail (grid-stride)
    for (int i = blockIdx.x * 512 + t; i < E; i += gridDim.x * 512)
        sidx[off[dstv[i]] + epos[i]] = src[i];
}

// ---------- k4: fused gather + epilogue ----------
__global__ __launch_bounds__(256) void k_gather(
    const unsigned char* __restrict__ yq, const bf16* __restrict__ z,
    const float* __restrict__ w,
    const int* __restrict__ off, const int* __restrict__ cnt, const int* __restrict__ sidx,
    const float* __restrict__ bl, const float* __restrict__ bres,
    const float* __restrict__ wscore, const float* __restrict__ bscore,
    const float* __restrict__ wcrit, const float* __restrict__ bcrit,
    const float* __restrict__ rrs, const float* __restrict__ palpha,
    int n, float* __restrict__ outF, float* __restrict__ outL)
{
    __shared__ bf16 wsb[11 * 128];
    int t = threadIdx.x;
    for (int i = t; i < 11 * 128; i += 256) {
        int q = i >> 7, c = i & 127;
        wsb[i] = (bf16)((q == 0) ? wscore[c] : wcrit[(size_t)(q - 1) * HDIM + c]);
    }
    __syncthreads();

    int node = blockIdx.x * 4 + (t >> 6);
    if (node >= n) return;
    int lane = t & 63, r2 = lane >> 5, c32 = lane & 31;

    uint2 zr = *(const uint2*)&z[(size_t)node * HDIM + c32 * 4];
    float wpre = (lane < 16) ? w[(size_t)node * 16 + lane] : 0.f;
    float4 blv = *(const float4*)&bl[c32 * 4];
    float4 brv = *(const float4*)&bres[c32 * 4];

    const unsigned char* ybase = yq + c32 * 4;
    int beg = off[node], len = cnt[node];
    const int* sp = sidx + beg;

    f32x2 a01 = {0.f, 0.f}, a23 = {0.f, 0.f};
    int e = 0;
    for (; e + 8 <= len; e += 8) {
        int i0 = sp[e + r2];
        int i1 = sp[e + 2 + r2];
        int i2 = sp[e + 4 + r2];
        int i3 = sp[e + 6 + r2];
        int v0 = *(const int*)(ybase + ((size_t)(unsigned)i0 << 7));
        int v1 = *(const int*)(ybase + ((size_t)(unsigned)i1 << 7));
        int v2 = *(const int*)(ybase + ((size_t)(unsigned)i2 << 7));
        int v3 = *(const int*)(ybase + ((size_t)(unsigned)i3 << 7));
        a01 += __builtin_amdgcn_cvt_pk_f32_fp8(v0, false)
             + __builtin_amdgcn_cvt_pk_f32_fp8(v1, false)
             + __builtin_amdgcn_cvt_pk_f32_fp8(v2, false)
             + __builtin_amdgcn_cvt_pk_f32_fp8(v3, false);
        a23 += __builtin_amdgcn_cvt_pk_f32_fp8(v0, true)
             + __builtin_amdgcn_cvt_pk_f32_fp8(v1, true)
             + __builtin_amdgcn_cvt_pk_f32_fp8(v2, true)
             + __builtin_amdgcn_cvt_pk_f32_fp8(v3, true);
    }
    for (; e < len; e += 2) {
        int slot = e + r2;
        int ii = sp[slot < len ? slot : len - 1];
        int v = *(const int*)(ybase + ((size_t)(unsigned)ii << 7));
        if (slot < len) {
            a01 += __builtin_amdgcn_cvt_pk_f32_fp8(v, false);
            a23 += __builtin_amdgcn_cvt_pk_f32_fp8(v, true);
        }
    }
    float a0 = a01[0], a1 = a01[1], a2 = a23[0], a3 = a23[1];
    a0 += __shfl_xor(a0, 32, 64);
    a1 += __shfl_xor(a1, 32, 64);
    a2 += __shfl_xor(a2, 32, 64);
    a3 += __shfl_xor(a3, 32, 64);
    float inv = 1.f / fmaxf((float)len, 1.f);

    // h' = relu(agg + bl + zr) + bres (Wres path folded into w; dot(bres) via brv here)
    float h0 = fmaxf(a0 * inv + blv.x + bflo(zr.x), 0.f) + brv.x;
    float h1 = fmaxf(a1 * inv + blv.y + bfhi(zr.x), 0.f) + brv.y;
    float h2 = fmaxf(a2 * inv + blv.z + bflo(zr.y), 0.f) + brv.z;
    float h3 = fmaxf(a3 * inv + blv.w + bfhi(zr.y), 0.f) + brv.w;

    float p[6], wq[6];
    #pragma unroll
    for (int qq = 0; qq < 6; qq++) {
        int q = r2 * 6 + qq;
        float s = 0.f;
        if (q < 11) {
            uint2 ww = *(const uint2*)&wsb[q * 128 + c32 * 4];
            s = h0 * bflo(ww.x) + h1 * bfhi(ww.x) + h2 * bflo(ww.y) + h3 * bfhi(ww.y);
        }
        #pragma unroll
        for (int d = 1; d < 32; d <<= 1)
            s += __shfl_xor(s, d, 64);
        p[qq] = s;
        wq[qq] = __shfl(wpre, (q < 11) ? q : 0, 64);
    }
    if ((lane & 31) == 0) {
        if (r2 == 0) {
            float al = palpha[0];
            float aa = 1.f / (1.f + expf(-al));
            outF[node] = aa * rrs[node] + (1.f - aa) * (p[0] + wq[0] + bscore[0]);
            #pragma unroll
            for (int qq = 1; qq < 6; qq++)
                outL[(size_t)node * NCRIT + qq - 1] = p[qq] + wq[qq] + bcrit[qq - 1];
        } else {
            #pragma unroll
            for (int qq = 0; qq < 5; qq++)
                outL[(size_t)node * NCRIT + 5 + qq] = p[qq] + wq[qq] + bcrit[5 + qq];
        }
    }
}

extern "C" void kernel_launch(void* const* d_in, const int* in_sizes, int n_in,
                              void* d_out, int out_size, void* d_ws, size_t ws_size,
                              hipStream_t stream) {
    const float* x      = (const float*)d_in[0];
    const int*   ei     = (const int*)d_in[1];
    const float* rrs    = (const float*)d_in[2];
    const float* Wl     = (const float*)d_in[3];
    const float* bl     = (const float*)d_in[4];
    const float* Wr     = (const float*)d_in[5];
    const float* Wres   = (const float*)d_in[6];
    const float* bres   = (const float*)d_in[7];
    const float* wscore = (const float*)d_in[8];
    const float* bscore = (const float*)d_in[9];
    const float* wcrit  = (const float*)d_in[10];
    const float* bcrit  = (const float*)d_in[11];
    const float* alpha  = (const float*)d_in[12];

    int N = in_sizes[0] / DIN;
    int E = in_sizes[1] / 2;
    const int* srcv = ei;
    const int* dstv = ei + E;

    char* p = (char*)d_ws;
    size_t cntPad = alignup((size_t)N * 4, 256);
    int* cnt   = (int*)p; p += cntPad;
    int* total = (int*)p; p += 256;
    int* off   = (int*)p; p += alignup((size_t)N * 4, 256);
    int* epos  = (int*)p; p += alignup((size_t)E * 4, 256);
    int* sidx  = (int*)p; p += alignup((size_t)E * 4, 256);
    bf16* WcatT = (bf16*)p; p += alignup((size_t)32 * 272 * 16, 256);
    unsigned char* yq = (unsigned char*)p; p += alignup((size_t)N * HDIM, 256);
    bf16* z    = (bf16*)p; p += alignup((size_t)N * HDIM * 2, 256);
    float* w   = (float*)p; p += alignup((size_t)N * 16 * 4, 256);

    hipMemsetAsync(cnt, 0, cntPad + 256, stream);

    int nW = 80;   // 64 wconv + 16 Wcomb
    k_histw<<<nW + (E + 255) / 256, 256, 0, stream>>>(dstv, E, cnt, epos, nW,
                                                      Wl, Wr, Wres, wscore, wcrit, WcatT);
    k_alloc<<<(N + 255) / 256, 256, 0, stream>>>(cnt, N, off, total);

    k_gemm<<<256, 512, 0, stream>>>(x, WcatT, N, yq, z, w,
                                    srcv, dstv, epos, E, off, sidx);

    float* outF = (float*)d_out;
    float* outL = outF + N;
    k_gather<<<(N + 3) / 4, 256, 0, stream>>>(yq, z, w, off, cnt, sidx, bl, bres,
                                              wscore, bscore, wcrit, bcrit,
                                              rrs, alpha, N, outF, outL);
}

// Round 17
// 239.799 us; speedup vs baseline: 2.1551x; 2.1551x over previous
//
#include <hip/hip_runtime.h>
#include <math.h>

#define DIN 256
#define HDIM 128
#define NCRIT 10

typedef __bf16 bf16;
typedef bf16 bf16x8 __attribute__((ext_vector_type(8)));
typedef float f32x4 __attribute__((ext_vector_type(4)));
typedef float f32x2 __attribute__((ext_vector_type(2)));

static inline size_t alignup(size_t x, size_t a) { return (x + a - 1) & ~(a - 1); }

__device__ inline float bflo(unsigned v) { return __uint_as_float(v << 16); }
__device__ inline float bfhi(unsigned v) { return __uint_as_float(v & 0xffff0000u); }

__device__ inline bf16x8 cvt8(float4 v0, float4 v1) {
    bf16x8 w;
    w[0] = (bf16)v0.x; w[1] = (bf16)v0.y; w[2] = (bf16)v0.z; w[3] = (bf16)v0.w;
    w[4] = (bf16)v1.x; w[5] = (bf16)v1.y; w[6] = (bf16)v1.z; w[7] = (bf16)v1.w;
    return w;
}

__device__ inline void gl_lds16(const void* g, void* l) {
    __builtin_amdgcn_global_load_lds(
        (const __attribute__((address_space(1))) unsigned*)g,
        (__attribute__((address_space(3))) unsigned*)l, 16, 0, 0);
}

// ---------- k1: build WcatT (chunk layout) + hist ----------
// Logical Wcat rows 0..127=Wl, 128..255=Wr, 256..266=Wepi@Wres, 267..271=0.
// WcatT: element (row c, k) at byte ((k>>3)*272 + c)*16 + (k&7)*2
__global__ void k_histw(const int* __restrict__ dst, int E, int* __restrict__ cnt,
                        int* __restrict__ epos, int nW,
                        const float* __restrict__ Wl, const float* __restrict__ Wr,
                        const float* __restrict__ Wres,
                        const float* __restrict__ wscore, const float* __restrict__ wcrit,
                        bf16* __restrict__ WcatT) {
    int t = threadIdx.x;
    int b = blockIdx.x;
    if (b < 64) {
        int base = (b * 256 + t) * 4;
        int r = base >> 8;
        int c0 = base & 255;
        const float* W = (r < 128) ? Wl : Wr;
        float4 v = *(const float4*)&W[(size_t)(r & 127) * 256 + c0];
        bf16 o[4] = {(bf16)v.x, (bf16)v.y, (bf16)v.z, (bf16)v.w};
        char* d = (char*)WcatT + ((((size_t)(c0 >> 3) * 272 + r) << 4) + ((c0 & 7) << 1));
        *(uint2*)d = *(const uint2*)o;
    } else if (b < 80) {
        int q = b - 64;
        int k = t;
        float s = 0.f;
        if (q < 11) {
            const float* wepi = (q == 0) ? wscore : &wcrit[(size_t)(q - 1) * HDIM];
            for (int c = 0; c < HDIM; ++c)
                s += wepi[c] * Wres[(size_t)c * 256 + k];
        }
        char* d = (char*)WcatT + ((((size_t)(k >> 3) * 272 + 256 + q) << 4) + ((k & 7) << 1));
        *(bf16*)d = (bf16)s;
    } else {
        int i = (b - nW) * 256 + t;
        if (i < E) epos[i] = atomicAdd(&cnt[dst[i]], 1);
    }
}

// ---------- k2: alloc (wave scan + atomic base) ----------
__global__ void k_alloc(const int* __restrict__ cnt, int n, int* __restrict__ off,
                        int* __restrict__ total) {
    int i = blockIdx.x * 256 + threadIdx.x;
    int lane = threadIdx.x & 63;
    int v = (i < n) ? cnt[i] : 0;
    int s = v;
    #pragma unroll
    for (int d = 1; d < 64; d <<= 1) {
        int t = __shfl_up(s, d, 64);
        if (lane >= d) s += t;
    }
    int excl = s - v;
    int wtot = __shfl(s, 63, 64);
    int base = 0;
    if (lane == 63) base = atomicAdd(total, wtot);
    base = __shfl(base, 63, 64);
    if (i < n) off[i] = base + excl;
}

// ---------- k3: barrier-free GEMM (B in LDS conflict-free, x reg-preload,
//             per-wave scratch epilogue w/ vector stores) + scatter tail ----------
__global__ __launch_bounds__(512) void k_gemm(
    const float* __restrict__ x, const bf16* __restrict__ WcatT, int n,
    unsigned char* __restrict__ yq, bf16* __restrict__ z, float* __restrict__ w,
    const int* __restrict__ src, const int* __restrict__ dstv,
    const int* __restrict__ epos, int E,
    const int* __restrict__ off, int* __restrict__ sidx)
{
    __shared__ __align__(16) char smem[147456];   // 136KB B + 8KB wave scratch
    int t = threadIdx.x;
    int wv = t >> 6, lane = t & 63;
    int l15 = lane & 15, kq = lane >> 4;

    // stage B: linear 136KB copy via global_load_lds (coalesced, conflict-free)
    {
        int cbase0 = wv * 64;
        #pragma unroll
        for (int i = 0; i < 17; i++) {
            int cbase = i * 512 + cbase0;
            gl_lds16((const char*)WcatT + (((size_t)cbase + lane) << 4),
                     smem + ((size_t)cbase << 4));
        }
    }
    __syncthreads();   // the only block-wide barrier

    char* scr = smem + 139264 + wv * 1024;   // per-wave 16x16 f32 scratch
    int rrow = lane >> 2, rc4 = (lane & 3) * 4;

    int nTiles = (n + 127) >> 7;
    for (int tile = blockIdx.x; tile < nTiles; tile += gridDim.x) {
        int rowb = tile * 128 + wv * 16;
        int myrow = rowb + l15;
        const float* ap = x + (size_t)(myrow < n ? myrow : (n - 1)) * 256 + kq * 8;

        // preload whole tile's x into registers (16 loads in flight)
        float4 xa[8], xb[8];
        #pragma unroll
        for (int s = 0; s < 8; s++) {
            xa[s] = *(const float4*)(ap + s * 32);
            xb[s] = *(const float4*)(ap + s * 32 + 4);
        }

        f32x4 acc[17];
        #pragma unroll
        for (int C = 0; C < 17; C++) acc[C] = (f32x4){0.f, 0.f, 0.f, 0.f};

        #pragma unroll
        for (int s = 0; s < 8; s++) {
            bf16x8 afr = cvt8(xa[s], xb[s]);
            int sbase = ((s * 4 + kq) * 272 + l15) << 4;
            #pragma unroll
            for (int C = 0; C < 17; C++) {
                bf16x8 b = *(const bf16x8*)(smem + sbase + C * 256);
                acc[C] = __builtin_amdgcn_mfma_f32_16x16x32_bf16(afr, b, acc[C], 0, 0, 0);
            }
        }

        // epilogue via per-wave scratch; all global stores >= 4B/lane, contiguous
        int gr = rowb + rrow;
        bool ok = gr < n;
        #pragma unroll
        for (int C = 0; C < 17; C++) {
            #pragma unroll
            for (int j = 0; j < 4; j++)
                *(float*)(scr + ((((kq << 2) + j) * 16 + l15) << 2)) = acc[C][j];
            f32x4 vv = *(const f32x4*)(scr + ((rrow * 16 + rc4) << 2));
            if (C < 8) {
                unsigned pk = (unsigned)__builtin_amdgcn_cvt_pk_fp8_f32(vv[0], vv[1], 0, false);
                pk = (unsigned)__builtin_amdgcn_cvt_pk_fp8_f32(vv[2], vv[3], pk, true);
                if (ok) *(unsigned*)(yq + (size_t)gr * 128 + C * 16 + rc4) = pk;
            } else if (C < 16) {
                bf16 o[4] = {(bf16)vv[0], (bf16)vv[1], (bf16)vv[2], (bf16)vv[3]};
                if (ok) *(uint2*)((char*)z + (size_t)gr * 256 + (C - 8) * 32 + rc4 * 2) =
                            *(const uint2*)o;
            } else {
                if (ok) *(f32x4*)(w + (size_t)gr * 16 + rc4) = vv;
            }
        }
    }

    // scatter tail (grid-stride)
    for (int i = blockIdx.x * 512 + t; i < E; i += gridDim.x * 512)
        sidx[off[dstv[i]] + epos[i]] = src[i];
}

// ---------- k4: fused gather + epilogue ----------
__global__ __launch_bounds__(256) void k_gather(
    const unsigned char* __restrict__ yq, const bf16* __restrict__ z,
    const float* __restrict__ w,
    const int* __restrict__ off, const int* __restrict__ cnt, const int* __restrict__ sidx,
    const float* __restrict__ bl, const float* __restrict__ bres,
    const float* __restrict__ wscore, const float* __restrict__ bscore,
    const float* __restrict__ wcrit, const float* __restrict__ bcrit,
    const float* __restrict__ rrs, const float* __restrict__ palpha,
    int n, float* __restrict__ outF, float* __restrict__ outL)
{
    __shared__ bf16 wsb[11 * 128];
    int t = threadIdx.x;
    for (int i = t; i < 11 * 128; i += 256) {
        int q = i >> 7, c = i & 127;
        wsb[i] = (bf16)((q == 0) ? wscore[c] : wcrit[(size_t)(q - 1) * HDIM + c]);
    }
    __syncthreads();

    int node = blockIdx.x * 4 + (t >> 6);
    if (node >= n) return;
    int lane = t & 63, r2 = lane >> 5, c32 = lane & 31;

    uint2 zr = *(const uint2*)&z[(size_t)node * HDIM + c32 * 4];
    float wpre = (lane < 16) ? w[(size_t)node * 16 + lane] : 0.f;
    float4 blv = *(const float4*)&bl[c32 * 4];
    float4 brv = *(const float4*)&bres[c32 * 4];

    const unsigned char* ybase = yq + c32 * 4;
    int beg = off[node], len = cnt[node];
    const int* sp = sidx + beg;

    f32x2 a01 = {0.f, 0.f}, a23 = {0.f, 0.f};
    int e = 0;
    for (; e + 8 <= len; e += 8) {
        int i0 = sp[e + r2];
        int i1 = sp[e + 2 + r2];
        int i2 = sp[e + 4 + r2];
        int i3 = sp[e + 6 + r2];
        int v0 = *(const int*)(ybase + ((size_t)(unsigned)i0 << 7));
        int v1 = *(const int*)(ybase + ((size_t)(unsigned)i1 << 7));
        int v2 = *(const int*)(ybase + ((size_t)(unsigned)i2 << 7));
        int v3 = *(const int*)(ybase + ((size_t)(unsigned)i3 << 7));
        a01 += __builtin_amdgcn_cvt_pk_f32_fp8(v0, false)
             + __builtin_amdgcn_cvt_pk_f32_fp8(v1, false)
             + __builtin_amdgcn_cvt_pk_f32_fp8(v2, false)
             + __builtin_amdgcn_cvt_pk_f32_fp8(v3, false);
        a23 += __builtin_amdgcn_cvt_pk_f32_fp8(v0, true)
             + __builtin_amdgcn_cvt_pk_f32_fp8(v1, true)
             + __builtin_amdgcn_cvt_pk_f32_fp8(v2, true)
             + __builtin_amdgcn_cvt_pk_f32_fp8(v3, true);
    }
    for (; e < len; e += 2) {
        int slot = e + r2;
        int ii = sp[slot < len ? slot : len - 1];
        int v = *(const int*)(ybase + ((size_t)(unsigned)ii << 7));
        if (slot < len) {
            a01 += __builtin_amdgcn_cvt_pk_f32_fp8(v, false);
            a23 += __builtin_amdgcn_cvt_pk_f32_fp8(v, true);
        }
    }
    float a0 = a01[0], a1 = a01[1], a2 = a23[0], a3 = a23[1];
    a0 += __shfl_xor(a0, 32, 64);
    a1 += __shfl_xor(a1, 32, 64);
    a2 += __shfl_xor(a2, 32, 64);
    a3 += __shfl_xor(a3, 32, 64);
    float inv = 1.f / fmaxf((float)len, 1.f);

    float h0 = fmaxf(a0 * inv + blv.x + bflo(zr.x), 0.f) + brv.x;
    float h1 = fmaxf(a1 * inv + blv.y + bfhi(zr.x), 0.f) + brv.y;
    float h2 = fmaxf(a2 * inv + blv.z + bflo(zr.y), 0.f) + brv.z;
    float h3 = fmaxf(a3 * inv + blv.w + bfhi(zr.y), 0.f) + brv.w;

    float p[6], wq[6];
    #pragma unroll
    for (int qq = 0; qq < 6; qq++) {
        int q = r2 * 6 + qq;
        float s = 0.f;
        if (q < 11) {
            uint2 ww = *(const uint2*)&wsb[q * 128 + c32 * 4];
            s = h0 * bflo(ww.x) + h1 * bfhi(ww.x) + h2 * bflo(ww.y) + h3 * bfhi(ww.y);
        }
        #pragma unroll
        for (int d = 1; d < 32; d <<= 1)
            s += __shfl_xor(s, d, 64);
        p[qq] = s;
        wq[qq] = __shfl(wpre, (q < 11) ? q : 0, 64);
    }
    if ((lane & 31) == 0) {
        if (r2 == 0) {
            float al = palpha[0];
            float aa = 1.f / (1.f + expf(-al));
            outF[node] = aa * rrs[node] + (1.f - aa) * (p[0] + wq[0] + bscore[0]);
            #pragma unroll
            for (int qq = 1; qq < 6; qq++)
                outL[(size_t)node * NCRIT + qq - 1] = p[qq] + wq[qq] + bcrit[qq - 1];
        } else {
            #pragma unroll
            for (int qq = 0; qq < 5; qq++)
                outL[(size_t)node * NCRIT + 5 + qq] = p[qq] + wq[qq] + bcrit[5 + qq];
        }
    }
}

extern "C" void kernel_launch(void* const* d_in, const int* in_sizes, int n_in,
                              void* d_out, int out_size, void* d_ws, size_t ws_size,
                              hipStream_t stream) {
    const float* x      = (const float*)d_in[0];
    const int*   ei     = (const int*)d_in[1];
    const float* rrs    = (const float*)d_in[2];
    const float* Wl     = (const float*)d_in[3];
    const float* bl     = (const float*)d_in[4];
    const float* Wr     = (const float*)d_in[5];
    const float* Wres   = (const float*)d_in[6];
    const float* bres   = (const float*)d_in[7];
    const float* wscore = (const float*)d_in[8];
    const float* bscore = (const float*)d_in[9];
    const float* wcrit  = (const float*)d_in[10];
    const float* bcrit  = (const float*)d_in[11];
    const float* alpha  = (const float*)d_in[12];

    int N = in_sizes[0] / DIN;
    int E = in_sizes[1] / 2;
    const int* srcv = ei;
    const int* dstv = ei + E;

    char* p = (char*)d_ws;
    size_t cntPad = alignup((size_t)N * 4, 256);
    int* cnt   = (int*)p; p += cntPad;
    int* total = (int*)p; p += 256;
    int* off   = (int*)p; p += alignup((size_t)N * 4, 256);
    int* epos  = (int*)p; p += alignup((size_t)E * 4, 256);
    int* sidx  = (int*)p; p += alignup((size_t)E * 4, 256);
    bf16* WcatT = (bf16*)p; p += alignup((size_t)32 * 272 * 16, 256);
    unsigned char* yq = (unsigned char*)p; p += alignup((size_t)N * HDIM, 256);
    bf16* z    = (bf16*)p; p += alignup((size_t)N * HDIM * 2, 256);
    float* w   = (float*)p; p += alignup((size_t)N * 16 * 4, 256);

    hipMemsetAsync(cnt, 0, cntPad + 256, stream);

    int nW = 80;   // 64 wconv + 16 Wcomb
    k_histw<<<nW + (E + 255) / 256, 256, 0, stream>>>(dstv, E, cnt, epos, nW,
                                                      Wl, Wr, Wres, wscore, wcrit, WcatT);
    k_alloc<<<(N + 255) / 256, 256, 0, stream>>>(cnt, N, off, total);

    k_gemm<<<256, 512, 0, stream>>>(x, WcatT, N, yq, z, w,
                                    srcv, dstv, epos, E, off, sidx);

    float* outF = (float*)d_out;
    float* outL = outF + N;
    k_gather<<<(N + 3) / 4, 256, 0, stream>>>(yq, z, w, off, cnt, sidx, bl, bres,
                                              wscore, bscore, wcrit, bcrit,
                                              rrs, alpha, N, outF, outL);
}